// Round 5
// baseline (15612.907 us; speedup 1.0000x reference)
//
#include <hip/hip_runtime.h>
#include <cstddef>

// Problem constants
#define NV   30
#define NDH  512
#define NE   256
#define NKV  128
#define NB   256
#define NT   800
#define NL   300
#define NKX  896   // E + KV + DH

#define PRED_SIZE (NB*NL*NV)   // predictions; attn_plot (NL*NT) follows

typedef float v4f __attribute__((ext_vector_type(4)));
typedef short bf16x8 __attribute__((ext_vector_type(8)));
typedef unsigned short ushort_t;

// workspace float offsets
#define OFF_C1   0                      // C1[512][256]  ([j][b])
#define OFF_C2   131072                 // C2[512? no: [j2 128][256]] -> [128*... see below
#define OFF_H2F  163840                 // H2f[256][128] ([b][j2]) fp32
#define OFF_XB   196608                 // Xb ushort[2 plane][256][1024]  (hi, lo)
#define OFF_XH2  458752                 // Xh2 ushort[2 pp][2 plane][256][128]
#define OFF_WF   524288                 // Wf  ushort[2][128][28][64][8]
#define OFF_WF2  2359296                // Wf2 ushort[2][32][20][64][8]
#define OFF_BS1  2686976                // bsum1[2048]
#define OFF_BS2  2689024                // bsum2[512]
// end 2689536 floats = 10.8 MB

#define WF_PL   ((size_t)128*28*64*8)   // Wf plane stride (ushorts)
#define WF2_PL  ((size_t)32*20*64*8)    // Wf2 plane stride (ushorts)

struct DecParams {
  const float* key; const float* val; const int* elen; const int* y;
  const float* emb;
  const float* wi1; const float* wh1; const float* bi1; const float* bh1;
  const float* wi2; const float* wh2; const float* bi2; const float* bh2;
  const float* ob;
  float* out; float* ws;
};

__device__ __forceinline__ float sigm(float x)  { return 1.0f/(1.0f + __expf(-x)); }
__device__ __forceinline__ float tanh_f(float x){ return 1.0f - 2.0f/(__expf(2.0f*x)+1.0f); }

__device__ __forceinline__ ushort_t bf16_rne(float x){
  union { float f; unsigned u; } v; v.f = x;
  unsigned r = v.u + 0x7FFFu + ((v.u >> 16) & 1u);
  return (ushort_t)(r >> 16);
}
__device__ __forceinline__ float bf16_to_f(ushort_t h){
  union { float f; unsigned u; } v; v.u = ((unsigned)h) << 16;
  return v.f;
}

// ---------------- init: zero C1/C2/H2f/Xb/Xh2 (floats 0..524288) ----------------
__global__ void __launch_bounds__(256)
k_init(DecParams P)
{
  P.ws[blockIdx.x * 256 + threadIdx.x] = 0.0f;   // grid 2048
}

// ---------------- initX: Xb ctx rows <- value[:,0,:] (emb/h1 rows stay 0) ----------------
__global__ void __launch_bounds__(256)
k_initX(DecParams P)
{
  const int b = blockIdx.x, tid = threadIdx.x;
  if (tid < 128) {
    ushort_t* xbh = (ushort_t*)(P.ws + OFF_XB);
    ushort_t* xbl = xbh + (size_t)256*1024;
    const float v = P.val[(size_t)b*NT*NKV + tid];
    const ushort_t hi = bf16_rne(v);
    const ushort_t lo = bf16_rne(v - bf16_to_f(hi));
    xbh[(size_t)b*1024 + 256 + tid] = hi;
    xbl[(size_t)b*1024 + 256 + tid] = lo;
  }
}

// ---------------- initW: W1 -> split-bf16 fragment-linear Wf; bsum1 ----------------
// Wf[plane][rt16][kc][lane][e]: lane = (r&15) | (((k>>3)&3)<<4), e = k&7
__global__ void __launch_bounds__(256)
k_initW(DecParams P)
{
  const int r = blockIdx.x;            // 0..2047
  const int tid = threadIdx.x;
  ushort_t* wf = (ushort_t*)(P.ws + OFF_WF);
  const int rt = r >> 4;
#pragma unroll
  for (int i = 0; i < 4; ++i) {
    const int k = i*256 + tid;
    if (k < NKX) {
      const float w = (k < 384) ? P.wi1[(size_t)r*384 + k]
                                : P.wh1[(size_t)r*512 + (k - 384)];
      const ushort_t hi = bf16_rne(w);
      const ushort_t lo = bf16_rne(w - bf16_to_f(hi));
      const int kc = k >> 5;
      const int lane = (r & 15) | (((k >> 3) & 3) << 4);
      const int e = k & 7;
      const size_t base = ((((size_t)rt)*28 + kc)*64 + lane)*8 + e;
      wf[base] = hi;
      wf[WF_PL + base] = lo;
    }
  }
  if (tid == 0) P.ws[OFF_BS1 + r] = P.bi1[r] + P.bh1[r];
}

// ---------------- initW2: [w_ih2 | w_hh2] -> Wf2; bsum2 ----------------
__global__ void __launch_bounds__(256)
k_initW2(DecParams P)
{
  const int r = blockIdx.x;            // 0..511
  const int tid = threadIdx.x;
  ushort_t* wf = (ushort_t*)(P.ws + OFF_WF2);
  const int rt = r >> 4;
#pragma unroll
  for (int i = 0; i < 3; ++i) {
    const int k = i*256 + tid;
    if (k < 640) {
      const float w = (k < 512) ? P.wi2[(size_t)r*512 + k]
                                : P.wh2[(size_t)r*128 + (k - 512)];
      const ushort_t hi = bf16_rne(w);
      const ushort_t lo = bf16_rne(w - bf16_to_f(hi));
      const int kc = k >> 5;
      const int lane = (r & 15) | (((k >> 3) & 3) << 4);
      const int e = k & 7;
      const size_t base = ((((size_t)rt)*20 + kc)*64 + lane)*8 + e;
      wf[base] = hi;
      wf[WF2_PL + base] = lo;
    }
  }
  if (tid == 0) P.ws[OFF_BS2 + r] = P.bi2[r] + P.bh2[r];
}

// ---------------- Phase A: LSTM1 fused (split-bf16 MFMA + activations) ----------------
// grid 256 = mt(32: 16 j) x nt(8: 32 b); 4 waves = 4 gates; wave rows rt16 = w*32+mt
__global__ void __launch_bounds__(256)
k_stepA(DecParams P)
{
  __shared__ ushort_t xs[2][32][136];   // [plane][b][128k + pad8]
  __shared__ float gbuf[4][16][33];     // [gate][j][b]
  const int tid = threadIdx.x, bid = blockIdx.x;
  const int mt = bid & 31, nt = bid >> 5;
  const int b0 = nt * 32, j0 = mt * 16;
  const int w = tid >> 6, lane = tid & 63;
  const int rt16 = w*32 + mt;

  const ushort_t* Wf  = (const ushort_t*)(P.ws + OFF_WF);
  const ushort_t* XbH = (const ushort_t*)(P.ws + OFF_XB);
  const ushort_t* XbL = XbH + (size_t)256*1024;
  float* C1 = P.ws + OFF_C1;
  const float* BS1 = P.ws + OFF_BS1;

  v4f acc[2] = {(v4f)0.0f, (v4f)0.0f};
  const int srow = tid >> 3, sk = (tid & 7) * 16;
  const int lr = lane & 15, lk8 = (lane >> 4) * 8;

#pragma unroll 1
  for (int p = 0; p < 7; ++p) {
    __syncthreads();
    {  // stage 128 k x 32 b, both planes
      const ushort_t* s0 = XbH + (size_t)(b0 + srow)*1024 + p*128 + sk;
      const ushort_t* s1 = XbL + (size_t)(b0 + srow)*1024 + p*128 + sk;
      *(bf16x8*)&xs[0][srow][sk]     = ((const bf16x8*)s0)[0];
      *(bf16x8*)&xs[0][srow][sk + 8] = ((const bf16x8*)s0)[1];
      *(bf16x8*)&xs[1][srow][sk]     = ((const bf16x8*)s1)[0];
      *(bf16x8*)&xs[1][srow][sk + 8] = ((const bf16x8*)s1)[1];
    }
    __syncthreads();
#pragma unroll
    for (int kc2 = 0; kc2 < 4; ++kc2) {
      const int kcg = p*4 + kc2;
      bf16x8 ah = *(const bf16x8*)(Wf + (((size_t)rt16*28 + kcg)*64 + lane)*8);
      bf16x8 al = *(const bf16x8*)(Wf + WF_PL + (((size_t)rt16*28 + kcg)*64 + lane)*8);
      const int lk = kc2*32 + lk8;
#pragma unroll
      for (int ct = 0; ct < 2; ++ct) {
        bf16x8 bh = *(const bf16x8*)&xs[0][ct*16 + lr][lk];
        bf16x8 bl = *(const bf16x8*)&xs[1][ct*16 + lr][lk];
        acc[ct] = __builtin_amdgcn_mfma_f32_16x16x32_bf16(ah, bh, acc[ct], 0, 0, 0);
        acc[ct] = __builtin_amdgcn_mfma_f32_16x16x32_bf16(ah, bl, acc[ct], 0, 0, 0);
        acc[ct] = __builtin_amdgcn_mfma_f32_16x16x32_bf16(al, bh, acc[ct], 0, 0, 0);
      }
    }
  }
  // epilogue: D col=lane&15 (b), row=(lane>>4)*4+reg (j)
  __syncthreads();
  const int rg = (lane >> 4) * 4;
#pragma unroll
  for (int ct = 0; ct < 2; ++ct)
#pragma unroll
    for (int j = 0; j < 4; ++j)
      gbuf[w][rg + j][ct*16 + lr] = acc[ct][j];
  __syncthreads();

  // activations: 16 j x 32 b
  ushort_t* XbHw = (ushort_t*)(P.ws + OFF_XB);
  ushort_t* XbLw = XbHw + (size_t)256*1024;
#pragma unroll
  for (int it = 0; it < 2; ++it) {
    const int idx = it*256 + tid;
    const int jj = idx >> 5, bq = idx & 31;
    const int jg = j0 + jj, b = b0 + bq;
    const float iv = sigm (gbuf[0][jj][bq] + BS1[       jg]);
    const float fv = sigm (gbuf[1][jj][bq] + BS1[ 512 + jg]);
    const float gv = tanh_f(gbuf[2][jj][bq] + BS1[1024 + jg]);
    const float ov = sigm (gbuf[3][jj][bq] + BS1[1536 + jg]);
    const float cn = fv * C1[(size_t)jg*256 + b] + iv * gv;
    C1[(size_t)jg*256 + b] = cn;
    const float h = ov * tanh_f(cn);
    const ushort_t hi = bf16_rne(h);
    const ushort_t lo = bf16_rne(h - bf16_to_f(hi));
    XbHw[(size_t)b*1024 + 384 + jg] = hi;
    XbLw[(size_t)b*1024 + 384 + jg] = lo;
  }
}

// ---------------- Phase B: LSTM2 fused (split-bf16 MFMA + activations) ----------------
// grid 64 = mt(8: 16 j2) x nt(8: 32 b); 4 waves = 4 gates; K=640 = h1(512)|h2prev(128)
__global__ void __launch_bounds__(256)
k_stepB(DecParams P, int t)
{
  __shared__ ushort_t xs[2][32][136];
  __shared__ float gbuf[4][16][33];
  const int tid = threadIdx.x, bid = blockIdx.x;
  const int mt = bid & 7, nt = bid >> 3;
  const int b0 = nt * 32, j0 = mt * 16;
  const int w = tid >> 6, lane = tid & 63;
  const int rt16 = w*8 + mt;

  const ushort_t* Wf2 = (const ushort_t*)(P.ws + OFF_WF2);
  const ushort_t* XbH = (const ushort_t*)(P.ws + OFF_XB);
  const ushort_t* XbL = XbH + (size_t)256*1024;
  const ushort_t* XH2 = (const ushort_t*)(P.ws + OFF_XH2);
  float* C2  = P.ws + OFF_C2;
  float* H2f = P.ws + OFF_H2F;
  const float* BS2 = P.ws + OFF_BS2;
  const int pp = t & 1, pn = (t + 1) & 1;

  v4f acc[2] = {(v4f)0.0f, (v4f)0.0f};
  const int srow = tid >> 3, sk = (tid & 7) * 16;
  const int lr = lane & 15, lk8 = (lane >> 4) * 8;

#pragma unroll 1
  for (int p = 0; p < 5; ++p) {
    __syncthreads();
    {
      const ushort_t* s0;
      const ushort_t* s1;
      if (p < 4) {
        s0 = XbH + (size_t)(b0 + srow)*1024 + 384 + p*128 + sk;
        s1 = XbL + (size_t)(b0 + srow)*1024 + 384 + p*128 + sk;
      } else {
        s0 = XH2 + ((size_t)(pp*2 + 0)*256 + b0 + srow)*128 + sk;
        s1 = XH2 + ((size_t)(pp*2 + 1)*256 + b0 + srow)*128 + sk;
      }
      *(bf16x8*)&xs[0][srow][sk]     = ((const bf16x8*)s0)[0];
      *(bf16x8*)&xs[0][srow][sk + 8] = ((const bf16x8*)s0)[1];
      *(bf16x8*)&xs[1][srow][sk]     = ((const bf16x8*)s1)[0];
      *(bf16x8*)&xs[1][srow][sk + 8] = ((const bf16x8*)s1)[1];
    }
    __syncthreads();
#pragma unroll
    for (int kc2 = 0; kc2 < 4; ++kc2) {
      const int kcg = p*4 + kc2;
      bf16x8 ah = *(const bf16x8*)(Wf2 + (((size_t)rt16*20 + kcg)*64 + lane)*8);
      bf16x8 al = *(const bf16x8*)(Wf2 + WF2_PL + (((size_t)rt16*20 + kcg)*64 + lane)*8);
      const int lk = kc2*32 + lk8;
#pragma unroll
      for (int ct = 0; ct < 2; ++ct) {
        bf16x8 bh = *(const bf16x8*)&xs[0][ct*16 + lr][lk];
        bf16x8 bl = *(const bf16x8*)&xs[1][ct*16 + lr][lk];
        acc[ct] = __builtin_amdgcn_mfma_f32_16x16x32_bf16(ah, bh, acc[ct], 0, 0, 0);
        acc[ct] = __builtin_amdgcn_mfma_f32_16x16x32_bf16(ah, bl, acc[ct], 0, 0, 0);
        acc[ct] = __builtin_amdgcn_mfma_f32_16x16x32_bf16(al, bh, acc[ct], 0, 0, 0);
      }
    }
  }
  __syncthreads();
  const int rg = (lane >> 4) * 4;
#pragma unroll
  for (int ct = 0; ct < 2; ++ct)
#pragma unroll
    for (int j = 0; j < 4; ++j)
      gbuf[w][rg + j][ct*16 + lr] = acc[ct][j];
  __syncthreads();

  ushort_t* XH2w = (ushort_t*)(P.ws + OFF_XH2);
#pragma unroll
  for (int it = 0; it < 2; ++it) {
    const int idx = it*256 + tid;
    const int jj = idx >> 5, bq = idx & 31;
    const int j2 = j0 + jj, b = b0 + bq;
    const float iv = sigm (gbuf[0][jj][bq] + BS2[      j2]);
    const float fv = sigm (gbuf[1][jj][bq] + BS2[128 + j2]);
    const float gv = tanh_f(gbuf[2][jj][bq] + BS2[256 + j2]);
    const float ov = sigm (gbuf[3][jj][bq] + BS2[384 + j2]);
    const float cn = fv * C2[(size_t)j2*256 + b] + iv * gv;
    C2[(size_t)j2*256 + b] = cn;
    const float h = ov * tanh_f(cn);
    H2f[(size_t)b*128 + j2] = h;
    const ushort_t hi = bf16_rne(h);
    const ushort_t lo = bf16_rne(h - bf16_to_f(hi));
    XH2w[((size_t)(pn*2 + 0)*256 + b)*128 + j2] = hi;
    XH2w[((size_t)(pn*2 + 1)*256 + b)*128 + j2] = lo;
  }
}

// ---------------- Phase C: attention + prediction + x_next ----------------
__global__ void __launch_bounds__(512)
k_stepC(DecParams P, int t)
{
  __shared__ float e[NT];
  __shared__ float qc[256];      // [h2 | ctx]
  __shared__ float red[16];
  __shared__ float ctxp[16][132];

  const int tid = threadIdx.x;
  const int b = blockIdx.x;
  const int len = P.elen[b];
  const float* H2f = P.ws + OFF_H2F;
  ushort_t* xbh = (ushort_t*)(P.ws + OFF_XB);
  ushort_t* xbl = xbh + (size_t)256*1024;

  if (tid < 128) qc[tid] = H2f[(size_t)b*128 + tid];
  __syncthreads();

  // ---- energy ----
  const int lg = tid & 15, grp = tid >> 4;
  const v4f qa = *(const v4f*)&qc[lg*8];
  const v4f qb = *(const v4f*)&qc[lg*8 + 4];
  const v4f* kb = (const v4f*)(P.key + (size_t)b*NT*NKV);
#pragma unroll 1
  for (int s = 0; s < 13; ++s) {
    const int ta = s*64 + grp, tb = ta + 32;
    float pa = 0.0f, pb = 0.0f;
    if (ta < len) {
      v4f k0 = kb[(size_t)ta*32 + lg*2], k1 = kb[(size_t)ta*32 + lg*2 + 1];
      v4f d = k0*qa + k1*qb; pa = d[0]+d[1]+d[2]+d[3];
    }
    if (tb < len) {
      v4f k0 = kb[(size_t)tb*32 + lg*2], k1 = kb[(size_t)tb*32 + lg*2 + 1];
      v4f d = k0*qa + k1*qb; pb = d[0]+d[1]+d[2]+d[3];
    }
    pa += __shfl_xor(pa, 1); pb += __shfl_xor(pb, 1);
    pa += __shfl_xor(pa, 2); pb += __shfl_xor(pb, 2);
    pa += __shfl_xor(pa, 4); pb += __shfl_xor(pb, 4);
    pa += __shfl_xor(pa, 8); pb += __shfl_xor(pb, 8);
    if (lg == 0) {
      if (ta < len) e[ta] = pa;
      if (tb < len) e[tb] = pb;
    }
  }
  for (int tt = len + tid; tt < NT; tt += 512) e[tt] = -1e9f;
  __syncthreads();

  // ---- softmax ----
  const int wid = tid >> 6;
  const float x0 = e[tid];
  const float x1 = (tid < NT - 512) ? e[512 + tid] : -3.0e38f;
  float m = fmaxf(x0, x1);
  m = fmaxf(m, __shfl_xor(m, 1));  m = fmaxf(m, __shfl_xor(m, 2));
  m = fmaxf(m, __shfl_xor(m, 4));  m = fmaxf(m, __shfl_xor(m, 8));
  m = fmaxf(m, __shfl_xor(m, 16)); m = fmaxf(m, __shfl_xor(m, 32));
  if ((tid & 63) == 0) red[wid] = m;
  __syncthreads();
  m = red[0];
#pragma unroll
  for (int i = 1; i < 8; ++i) m = fmaxf(m, red[i]);
  const float p0 = __expf(x0 - m);
  const float p1 = (tid < NT - 512) ? __expf(x1 - m) : 0.0f;
  float ss = p0 + p1;
  ss += __shfl_xor(ss, 1);  ss += __shfl_xor(ss, 2);  ss += __shfl_xor(ss, 4);
  ss += __shfl_xor(ss, 8);  ss += __shfl_xor(ss, 16); ss += __shfl_xor(ss, 32);
  if ((tid & 63) == 0) red[8 + wid] = ss;
  __syncthreads();
  float S = red[8];
#pragma unroll
  for (int i = 1; i < 8; ++i) S += red[8 + i];
  const float inv = 1.0f / S;
  e[tid] = p0 * inv;
  if (tid < NT - 512) e[512 + tid] = p1 * inv;
  if (b == 0) {
    P.out[PRED_SIZE + (size_t)t*NT + tid] = p0 * inv;
    if (tid < NT - 512) P.out[PRED_SIZE + (size_t)t*NT + 512 + tid] = p1 * inv;
  }
  __syncthreads();

  // ---- ctx = attn @ value ----
  {
    const int kq = tid & 31, tq = tid >> 5;
    const v4f* vb = (const v4f*)(P.val + (size_t)b*NT*NKV);
    v4f a4 = (v4f)0.0f, a42 = (v4f)0.0f;
    int tt = tq;
    for (; tt + 16 < len; tt += 32) {
      a4  += e[tt]      * vb[(size_t)tt*32 + kq];
      a42 += e[tt + 16] * vb[(size_t)(tt + 16)*32 + kq];
    }
    if (tt < len) a4 += e[tt] * vb[(size_t)tt*32 + kq];
    a4 += a42;
    *(v4f*)&ctxp[tq][kq*4] = a4;
  }
  __syncthreads();
  if (tid < 128) {
    const int k = tid;
    float c = 0.0f;
#pragma unroll
    for (int r = 0; r < 16; ++r) c += ctxp[r][k];
    qc[128 + k] = c;
    const ushort_t hi = bf16_rne(c);
    const ushort_t lo = bf16_rne(c - bf16_to_f(hi));
    xbh[(size_t)b*1024 + 256 + k] = hi;    // x_next ctx
    xbl[(size_t)b*1024 + 256 + k] = lo;
  }
  __syncthreads();

  // ---- pred = [h2|ctx] @ emb^T + bias ----
  {
    const int vv = tid >> 4, lg16 = tid & 15;
    if (vv < NV) {
      const v4f* er = (const v4f*)(P.emb + (size_t)vv*NE + lg16*16);
      const v4f* qr = (const v4f*)&qc[lg16*16];
      v4f s4 = er[0]*qr[0] + er[1]*qr[1] + er[2]*qr[2] + er[3]*qr[3];
      float p = s4[0] + s4[1] + s4[2] + s4[3];
      p += __shfl_xor(p, 1); p += __shfl_xor(p, 2);
      p += __shfl_xor(p, 4); p += __shfl_xor(p, 8);
      if (lg16 == 0) P.out[((size_t)b*NL + t)*NV + vv] = p + P.ob[vv];
    }
  }

  // ---- x_next: emb(y[b][t]) ----
  if (tid < 256) {
    const int tok = P.y[(size_t)b*NL + t];
    const float x = P.emb[(size_t)tok*NE + tid];
    const ushort_t hi = bf16_rne(x);
    const ushort_t lo = bf16_rne(x - bf16_to_f(hi));
    xbh[(size_t)b*1024 + tid] = hi;
    xbl[(size_t)b*1024 + tid] = lo;
  }
}

extern "C" void kernel_launch(void* const* d_in, const int* in_sizes, int n_in,
                              void* d_out, int out_size, void* d_ws, size_t ws_size,
                              hipStream_t stream) {
  (void)in_sizes; (void)n_in; (void)out_size; (void)ws_size;
  DecParams P;
  P.key  = (const float*)d_in[0];
  P.val  = (const float*)d_in[1];
  P.elen = (const int*)d_in[2];
  P.y    = (const int*)d_in[3];
  P.emb  = (const float*)d_in[4];
  P.wi1  = (const float*)d_in[5];
  P.wh1  = (const float*)d_in[6];
  P.bi1  = (const float*)d_in[7];
  P.bh1  = (const float*)d_in[8];
  P.wi2  = (const float*)d_in[9];
  P.wh2  = (const float*)d_in[10];
  P.bi2  = (const float*)d_in[11];
  P.bh2  = (const float*)d_in[12];
  P.ob   = (const float*)d_in[13];
  P.out  = (float*)d_out;
  P.ws   = (float*)d_ws;

  hipLaunchKernelGGL(k_init,   dim3(2048), dim3(256), 0, stream, P);
  hipLaunchKernelGGL(k_initX,  dim3(256),  dim3(256), 0, stream, P);
  hipLaunchKernelGGL(k_initW,  dim3(2048), dim3(256), 0, stream, P);
  hipLaunchKernelGGL(k_initW2, dim3(512),  dim3(256), 0, stream, P);
  for (int t = 0; t < NL; ++t) {
    hipLaunchKernelGGL(k_stepA, dim3(256), dim3(256), 0, stream, P);
    hipLaunchKernelGGL(k_stepB, dim3(64),  dim3(256), 0, stream, P, t);
    hipLaunchKernelGGL(k_stepC, dim3(NB),  dim3(512), 0, stream, P, t);
  }
}